// Round 8
// baseline (276.538 us; speedup 1.0000x reference)
//
#include <hip/hip_runtime.h>
#include <math.h>

#define ZQ_ELEMS 8388608
#define ZQ_OFF 1
#define PPLX_OFF (1 + ZQ_ELEMS)
#define IDX_OFF  (2 + ZQ_ELEMS)

typedef __attribute__((ext_vector_type(8))) short short8;
typedef __attribute__((ext_vector_type(4))) float f32x4;
typedef __attribute__((ext_vector_type(16))) float f32x16;

// ---- ws byte layout ----
// 0       : loss f32
// 256     : counts u32[1024]
// 8192    : candc u32[32768]      (zeroed)
// 139264  : safeflag u32[32768]   (zeroed)
// 270336  : lists u16[32768*24]
// 1843200 : w2 f32[1024]
// 1847296 : ebf_l ushort[262144]  codebook bf16 in MFMA fragment layout
#define WS_CANDC 8192
#define WS_FLAG  139264
#define WS_LIST  270336
#define WS_W2    1843200
#define WS_EBF   1847296

static __device__ __forceinline__ ushort f2bf(float f) {
    uint u = __float_as_uint(f);
    return (ushort)((u + 0x7fffu + ((u >> 16) & 1u)) >> 16);
}

__global__ __launch_bounds__(256) void vq_zero(uint* ws) {
    for (int i = blockIdx.x * 256 + threadIdx.x; i < 67584; i += 64 * 256) ws[i] = 0u;
}

// exact ||e_j||^2, ascending-k fmaf chain (bitwise identical to rounds 1/2/4)
__global__ __launch_bounds__(64) void vq_prep_w2(const float* __restrict__ w,
                                                 float* __restrict__ w2) {
    const int j = blockIdx.x * 64 + threadIdx.x;
    const float* wr = w + (size_t)j * 256;
    float s = 0.f;
    for (int k4 = 0; k4 < 64; ++k4) {
        float4 v = *(const float4*)(wr + k4 * 4);
        s = fmaf(v.x, v.x, s); s = fmaf(v.y, v.y, s);
        s = fmaf(v.z, v.z, s); s = fmaf(v.w, v.w, s);
    }
    w2[j] = s;
}

__global__ __launch_bounds__(256) void vq_prep_e(const float* __restrict__ w,
                                                 ushort* __restrict__ ebf_l) {
    const int g = blockIdx.x * 256 + threadIdx.x;
    const int j = g >> 5, o = g & 31;
    const float* src = w + (size_t)j * 256 + o * 8;
    float4 v0 = *(const float4*)src;
    float4 v1 = *(const float4*)(src + 4);
    short8 r;
    r[0] = (short)f2bf(v0.x); r[1] = (short)f2bf(v0.y);
    r[2] = (short)f2bf(v0.z); r[3] = (short)f2bf(v0.w);
    r[4] = (short)f2bf(v1.x); r[5] = (short)f2bf(v1.y);
    r[6] = (short)f2bf(v1.z); r[7] = (short)f2bf(v1.w);
    const size_t dst = (size_t)(j >> 5) * 8192 + (size_t)(o >> 1) * 512
                     + (size_t)((j & 31) + (o & 1) * 32) * 8;
    *(short8*)(ebf_l + dst) = r;
}

// K1: bf16 32x32x16-MFMA approx sweep. grid 1024 = 256 row-blocks x 4 j-quarters.
__global__ __launch_bounds__(256) void vq_sweep(const float* __restrict__ z,
                                                const ushort* __restrict__ ebf_l,
                                                const float* __restrict__ w2,
                                                uint* __restrict__ candc,
                                                uint* __restrict__ safeflag,
                                                ushort* __restrict__ lists) {
    __shared__ ushort lcl[128][16];
    __shared__ uint lcnt[128];
    __shared__ float sTr[128];

    const int t = threadIdx.x, wv = t >> 6, l = t & 63;
    const int jq = blockIdx.x & 3, rb = blockIdx.x >> 2;
    const int n0 = rb * 128 + wv * 32;
    const int b = n0 >> 10, hw0 = n0 & 1023;
    const int lj = l & 31, hi = l >> 5;

    for (int i = t; i < 128; i += 256) lcnt[i] = 0u;

    const float* zb = z + (size_t)b * 262144 + hw0 + lj;
    short8 as[16];
    float z2p = 0.f;
    #pragma unroll
    for (int s = 0; s < 16; ++s) {
        short8 fr;
        #pragma unroll
        for (int i = 0; i < 8; ++i) {
            const int k = s * 16 + hi * 8 + i;
            float f = zb[(size_t)k << 10];
            z2p = fmaf(f, f, z2p);
            fr[i] = (short)f2bf(f);
        }
        as[s] = fr;
    }
    z2p += __shfl_xor(z2p, 32);
    if (hi == 0) sTr[wv * 32 + lj] = -2.617e-3f * sqrtf(z2p);  // -2.32 sigma
    __syncthreads();

    int rloc[16];
    float TrW[16];
    #pragma unroll
    for (int q = 0; q < 16; ++q) {
        rloc[q] = wv * 32 + (q & 3) + 8 * (q >> 2) + 4 * hi;
        TrW[q] = sTr[rloc[q]];
    }

    const int jbase = jq * 256;
    float w2v[8];
    #pragma unroll
    for (int g = 0; g < 8; ++g) w2v[g] = w2[jbase + g * 32 + lj];

    uint safem = 0u;
    for (int g = 0; g < 8; ++g) {
        const ushort* bt = ebf_l + (size_t)(jq * 8 + g) * 8192;
        f32x16 acc = {};
        f32x16 acc2 = {};
        #pragma unroll
        for (int s = 0; s < 16; s += 2) {   // dual chain: halves dependent-MFMA latency
            short8 bf  = *(const short8*)(bt + s * 512 + l * 8);
            short8 bf2 = *(const short8*)(bt + (s + 1) * 512 + l * 8);
            acc  = __builtin_amdgcn_mfma_f32_32x32x16_bf16(as[s],     bf,  acc,  0, 0, 0);
            acc2 = __builtin_amdgcn_mfma_f32_32x32x16_bf16(as[s + 1], bf2, acc2, 0, 0, 0);
        }
        const int j = jbase + g * 32 + lj;
        float sv[16];
        bool anyhit = false;
        #pragma unroll
        for (int q = 0; q < 16; ++q) {
            sv[q] = fmaf(-2.f, acc[q] + acc2[q], w2v[g]);
            anyhit = anyhit || (sv[q] <= TrW[q]);
        }
        if (__any(anyhit)) {
            #pragma unroll
            for (int q = 0; q < 16; ++q)
                if (sv[q] <= TrW[q]) {
                    uint pos = atomicAdd(&lcnt[rloc[q]], 1u);
                    if (pos < 16u) lcl[rloc[q]][pos] = (ushort)j;
                    if (sv[q] <= TrW[q] - 1.5e-3f) safem |= (1u << q);
                }
        }
    }

    #pragma unroll
    for (int off = 1; off < 32; off <<= 1) safem |= __shfl_xor(safem, off);
    if (lj == 0) {
        #pragma unroll
        for (int q = 0; q < 16; ++q)
            if (safem & (1u << q)) safeflag[rb * 128 + rloc[q]] = 1u;
    }
    __syncthreads();

    if (t < 128) {
        const uint lc = lcnt[t];
        const int n = rb * 128 + t;
        if (lc > 16u) atomicAdd(&candc[n], 100u);
        else if (lc) {
            uint base = atomicAdd(&candc[n], lc);
            for (uint i = 0; i < lc && base + i < 24u; ++i)
                lists[(size_t)n * 24 + base + i] = lcl[t][i];
        }
    }
}

// K2a: exact fp32 argmin only (bitwise round-1/2/4 chains). 512 blocks, 64 rows each.
__global__ __launch_bounds__(256) void vq_argmin(const float* __restrict__ z,
                                                 const float* __restrict__ w,
                                                 const float* __restrict__ w2,
                                                 const uint* __restrict__ candc,
                                                 const uint* __restrict__ safeflag,
                                                 const ushort* __restrict__ lists,
                                                 float* __restrict__ out,
                                                 float* __restrict__ ws) {
    __shared__ float tile[256][64];
    __shared__ float sz2[64];
    __shared__ int sjmin[64];
    __shared__ int scnt[64];
    __shared__ int soff[65];
    __shared__ uint swl[1536];
    __shared__ float sd[1536];
    __shared__ unsigned long long sfbm;
    __shared__ unsigned long long sred[4];

    const int t = threadIdx.x;
    const int n0 = blockIdx.x * 64;
    const int b = n0 >> 10, hw0 = n0 & 1023;

    if (t == 0) sfbm = 0ull;

    {   // stage z tile transposed
        const int r4 = t & 15, cb = t >> 4;
        for (int i = 0; i < 16; ++i) {
            const int c = i * 16 + cb;
            float4 v = *(const float4*)(z + ((size_t)(b * 256 + c) << 10) + hw0 + r4 * 4);
            *(float4*)&tile[c][r4 * 4] = v;
        }
    }
    __syncthreads();

    if (t < 64) {   // exact z2 (ascending k)
        float s = 0.f;
        for (int k = 0; k < 256; ++k) { float v = tile[k][t]; s = fmaf(v, v, s); }
        sz2[t] = s;
    }
    if (t < 64) {
        const int n = n0 + t;
        uint c = candc[n];
        bool fb = (safeflag[n] == 0u) || (c == 0u) || (c > 24u);
        scnt[t] = fb ? 0 : (int)c;
        if (fb) atomicOr(&sfbm, 1ull << t);
    }
    __syncthreads();
    if (t == 0) {
        int acc = 0;
        for (int r = 0; r < 64; ++r) { soff[r] = acc; acc += scnt[r]; }
        soff[64] = acc;
    }
    __syncthreads();
    if (t < 64) {
        const int o = soff[t], c = scnt[t], n = n0 + t;
        for (int i = 0; i < c; ++i) swl[o + i] = ((uint)t << 16) | (uint)lists[(size_t)n * 24 + i];
    }
    __syncthreads();

    const int total = soff[64];
    for (int e = t; e < total; e += 256) {
        const int r = (int)(swl[e] >> 16);
        const int j = (int)(swl[e] & 0xffffu);
        const float* wr = w + ((size_t)j << 8);
        float dot = 0.f;
        for (int k4 = 0; k4 < 64; ++k4) {
            float4 v = *(const float4*)(wr + k4 * 4);
            const int k0 = k4 * 4;
            dot = fmaf(v.x, tile[k0 + 0][r], dot);
            dot = fmaf(v.y, tile[k0 + 1][r], dot);
            dot = fmaf(v.z, tile[k0 + 2][r], dot);
            dot = fmaf(v.w, tile[k0 + 3][r], dot);
        }
        const float u = sz2[r] + w2[j];
        sd[e] = u - 2.0f * dot;
    }
    __syncthreads();

    if (t < 64 && scnt[t] > 0) {
        float db = 1e30f; int jb = 0;
        const int o = soff[t], c = scnt[t];
        for (int i = 0; i < c; ++i) {
            float d = sd[o + i];
            int j = (int)(swl[o + i] & 0xffffu);
            if (d < db || (d == db && j < jb)) { db = d; jb = j; }
        }
        sjmin[t] = jb;
    }
    __syncthreads();

    // fallback rows: full exact block-wide scan
    unsigned long long fm = sfbm;
    while (fm) {
        const int r = __ffsll(fm) - 1;
        fm &= fm - 1;
        unsigned long long key = ~0ull;
        for (int jj = 0; jj < 4; ++jj) {
            const int j = t * 4 + jj;
            const float* wr = w + ((size_t)j << 8);
            float dot = 0.f;
            for (int k4 = 0; k4 < 64; ++k4) {
                float4 v = *(const float4*)(wr + k4 * 4);
                const int k0 = k4 * 4;
                dot = fmaf(v.x, tile[k0 + 0][r], dot);
                dot = fmaf(v.y, tile[k0 + 1][r], dot);
                dot = fmaf(v.z, tile[k0 + 2][r], dot);
                dot = fmaf(v.w, tile[k0 + 3][r], dot);
            }
            const float u = sz2[r] + w2[j];
            const float d = u - 2.0f * dot;
            unsigned long long kk = ((unsigned long long)__float_as_uint(d) << 32) | (uint)j;
            if (kk < key) key = kk;
        }
        #pragma unroll
        for (int off = 32; off >= 1; off >>= 1) {
            unsigned long long ok = __shfl_xor(key, off);
            if (ok < key) key = ok;
        }
        if ((t & 63) == 0) sred[t >> 6] = key;
        __syncthreads();
        if (t == 0) {
            unsigned long long kk = sred[0];
            for (int i = 1; i < 4; ++i) if (sred[i] < kk) kk = sred[i];
            sjmin[r] = (int)(kk & 0xffffffffull);
        }
        __syncthreads();
    }
    __syncthreads();

    // indices + perplexity counts
    if (t < 64) {
        const int j = sjmin[t];
        out[IDX_OFF + n0 + t] = (float)j;
        atomicAdd((uint*)ws + 64 + j, 1u);
    }
}

// K2b: streaming epilogue. 1024 blocks x 256 thr, 32 rows each; 4 blocks/CU.
__global__ __launch_bounds__(256) void vq_emit(const float* __restrict__ z,
                                               const float* __restrict__ w,
                                               float* __restrict__ out,
                                               float* __restrict__ ws) {
    __shared__ float tile[256][32];
    __shared__ int sj[32];
    __shared__ float lred[4];

    const int t = threadIdx.x;
    const int n0 = blockIdx.x * 32;
    const int b = n0 >> 10, hw0 = n0 & 1023;

    if (t < 32) sj[t] = (int)out[IDX_OFF + n0 + t];
    {   // stage z transposed (aligned float4 loads)
        const int r4 = t & 7, cb = t >> 3;
        for (int i = 0; i < 8; ++i) {
            const int c = i * 32 + cb;
            float4 v = *(const float4*)(z + ((size_t)(b * 256 + c) << 10) + hw0 + r4 * 4);
            *(float4*)&tile[c][r4 * 4] = v;
        }
    }
    __syncthreads();

    // gather codebook rows, loss, overwrite tile with z_q
    float lsum = 0.f;
    {
        const int r = t & 31, cq = t >> 5;   // cq 0..7
        const float* wrow = w + ((size_t)sj[r] << 8);
        for (int i = 0; i < 8; ++i) {
            const int c0 = (i * 8 + cq) * 4;
            float4 v = *(const float4*)(wrow + c0);
            float d0 = v.x - tile[c0 + 0][r];
            float d1 = v.y - tile[c0 + 1][r];
            float d2 = v.z - tile[c0 + 2][r];
            float d3 = v.w - tile[c0 + 3][r];
            lsum += d0 * d0 + d1 * d1 + d2 * d2 + d3 * d3;
            tile[c0 + 0][r] = v.x;
            tile[c0 + 1][r] = v.y;
            tile[c0 + 2][r] = v.z;
            tile[c0 + 3][r] = v.w;
        }
    }
    __syncthreads();

    // z_q (NCHW) write — dword-aligned coalesced stores (out+1 base)
    {
        const int r = t & 31, ch = (t >> 5) & 1, wv = t >> 6;
        for (int i = 0; i < 32; ++i) {
            const int c = i * 8 + wv * 2 + ch;
            out[ZQ_OFF + ((size_t)(b * 256 + c) << 10) + hw0 + r] = tile[c][r];
        }
    }

    for (int off = 32; off >= 1; off >>= 1) lsum += __shfl_xor(lsum, off, 64);
    if ((t & 63) == 0) lred[t >> 6] = lsum;
    __syncthreads();
    if (t == 0) atomicAdd(ws, lred[0] + lred[1] + lred[2] + lred[3]);
}

__global__ __launch_bounds__(1024) void vq_fin(float* __restrict__ out,
                                               float* __restrict__ ws) {
    __shared__ float red[16];
    const int t = threadIdx.x;
    const uint cnt = ((const uint*)ws)[64 + t];
    const float e = (float)cnt * (1.0f / 32768.0f);
    float s = e * logf(e + 1e-10f);
    for (int off = 32; off >= 1; off >>= 1) s += __shfl_xor(s, off, 64);
    if ((t & 63) == 0) red[t >> 6] = s;
    __syncthreads();
    if (t == 0) {
        float H = 0.f;
        for (int i = 0; i < 16; ++i) H += red[i];
        out[PPLX_OFF] = expf(-H);
        const float l = ws[0] * (1.0f / 8388608.0f);
        out[0] = l + 0.25f * l;
    }
}

extern "C" void kernel_launch(void* const* d_in, const int* in_sizes, int n_in,
                              void* d_out, int out_size, void* d_ws, size_t ws_size,
                              hipStream_t stream) {
    const float* z = (const float*)d_in[0];   // (32,256,32,32) f32
    const float* w = (const float*)d_in[1];   // (1024,256) f32
    float* out = (float*)d_out;
    float* ws = (float*)d_ws;

    uint* candc = (uint*)((char*)d_ws + WS_CANDC);
    uint* safeflag = (uint*)((char*)d_ws + WS_FLAG);
    ushort* lists = (ushort*)((char*)d_ws + WS_LIST);
    float* w2 = (float*)((char*)d_ws + WS_W2);
    ushort* ebf_l = (ushort*)((char*)d_ws + WS_EBF);

    vq_zero<<<64, 256, 0, stream>>>((uint*)d_ws);
    vq_prep_w2<<<16, 64, 0, stream>>>(w, w2);
    vq_prep_e<<<128, 256, 0, stream>>>(w, ebf_l);
    vq_sweep<<<1024, 256, 0, stream>>>(z, ebf_l, w2, candc, safeflag, lists);
    vq_argmin<<<512, 256, 0, stream>>>(z, w, w2, candc, safeflag, lists, out, ws);
    vq_emit<<<1024, 256, 0, stream>>>(z, w, out, ws);
    vq_fin<<<1, 1024, 0, stream>>>(out, ws);
}

// Round 10
// 251.275 us; speedup vs baseline: 1.1005x; 1.1005x over previous
//
#include <hip/hip_runtime.h>
#include <math.h>

#define ZQ_ELEMS 8388608
#define ZQ_OFF 1
#define PPLX_OFF (1 + ZQ_ELEMS)
#define IDX_OFF  (2 + ZQ_ELEMS)

typedef __attribute__((ext_vector_type(8))) short short8;
typedef __attribute__((ext_vector_type(16))) float f32x16;

// ---- ws byte layout ----
// 0       loss f32
// 256     counts u32[1024]
// 8192    candc u32[32768]     (zeroed)
// 139264  safeflag u32[32768]  (zeroed)
// 270336  lists u16[32768*24]
// 1843200 w2 f32[1024]
// 1847296 ebf_l ushort[262144] (bf16 codebook, MFMA fragment layout)
// 2371584 w_t f32[262144]      (transposed codebook [k][j])
// 3420160 fbq u32[1+32768]     (fallback queue: count + row ids)
#define WS_CANDC 8192
#define WS_FLAG  139264
#define WS_LIST  270336
#define WS_W2    1843200
#define WS_EBF   1847296
#define WS_WT    2371584
#define WS_FBQ   3420160

#define GLOAD_LDS16(gp, lp) \
    __builtin_amdgcn_global_load_lds((const __attribute__((address_space(1))) void*)(gp), \
                                     (__attribute__((address_space(3))) void*)(lp), 16, 0, 0)

static __device__ __forceinline__ ushort f2bf(float f) {
    uint u = __float_as_uint(f);
    return (ushort)((u + 0x7fffu + ((u >> 16) & 1u)) >> 16);
}

__global__ __launch_bounds__(256) void vq_zero(uint* ws) {
    for (int i = blockIdx.x * 256 + threadIdx.x; i < 67584; i += 64 * 256) ws[i] = 0u;
    if (blockIdx.x == 0 && threadIdx.x == 0) ws[WS_FBQ / 4] = 0u;   // fbq count
}

// exact ||e_j||^2, ascending-k fmaf chain (bitwise identical to rounds 1/2/4/8)
__global__ __launch_bounds__(64) void vq_prep_w2(const float* __restrict__ w,
                                                 float* __restrict__ w2) {
    const int j = blockIdx.x * 64 + threadIdx.x;
    const float* wr = w + (size_t)j * 256;
    float s = 0.f;
    for (int k4 = 0; k4 < 64; ++k4) {
        float4 v = *(const float4*)(wr + k4 * 4);
        s = fmaf(v.x, v.x, s); s = fmaf(v.y, v.y, s);
        s = fmaf(v.z, v.z, s); s = fmaf(v.w, v.w, s);
    }
    w2[j] = s;
}

__global__ __launch_bounds__(256) void vq_prep_e(const float* __restrict__ w,
                                                 ushort* __restrict__ ebf_l) {
    const int g = blockIdx.x * 256 + threadIdx.x;
    const int j = g >> 5, o = g & 31;
    const float* src = w + (size_t)j * 256 + o * 8;
    float4 v0 = *(const float4*)src;
    float4 v1 = *(const float4*)(src + 4);
    short8 r;
    r[0] = (short)f2bf(v0.x); r[1] = (short)f2bf(v0.y);
    r[2] = (short)f2bf(v0.z); r[3] = (short)f2bf(v0.w);
    r[4] = (short)f2bf(v1.x); r[5] = (short)f2bf(v1.y);
    r[6] = (short)f2bf(v1.z); r[7] = (short)f2bf(v1.w);
    const size_t dst = (size_t)(j >> 5) * 8192 + (size_t)(o >> 1) * 512
                     + (size_t)((j & 31) + (o & 1) * 32) * 8;
    *(short8*)(ebf_l + dst) = r;
}

// transposed codebook w_t[k][j] = w[j][k] (value copy -> exact chains unchanged)
__global__ __launch_bounds__(256) void vq_prep_wt(const float* __restrict__ w,
                                                  float* __restrict__ wt) {
    const int i = blockIdx.x * 256 + threadIdx.x;   // 1024 blocks -> 262144
    const int k = i >> 10, j = i & 1023;
    wt[i] = w[(size_t)j * 256 + k];
}

// K1: bf16 32x32x16-MFMA approx sweep (UNCHANGED - need its counters).
__global__ __launch_bounds__(256) void vq_sweep(const float* __restrict__ z,
                                                const ushort* __restrict__ ebf_l,
                                                const float* __restrict__ w2,
                                                uint* __restrict__ candc,
                                                uint* __restrict__ safeflag,
                                                ushort* __restrict__ lists) {
    __shared__ ushort lcl[128][16];
    __shared__ uint lcnt[128];
    __shared__ float sTr[128];

    const int t = threadIdx.x, wv = t >> 6, l = t & 63;
    const int jq = blockIdx.x & 3, rb = blockIdx.x >> 2;
    const int n0 = rb * 128 + wv * 32;
    const int b = n0 >> 10, hw0 = n0 & 1023;
    const int lj = l & 31, hi = l >> 5;

    for (int i = t; i < 128; i += 256) lcnt[i] = 0u;

    const float* zb = z + (size_t)b * 262144 + hw0 + lj;
    short8 as[16];
    float z2p = 0.f;
    #pragma unroll
    for (int s = 0; s < 16; ++s) {
        short8 fr;
        #pragma unroll
        for (int i = 0; i < 8; ++i) {
            const int k = s * 16 + hi * 8 + i;
            float f = zb[(size_t)k << 10];
            z2p = fmaf(f, f, z2p);
            fr[i] = (short)f2bf(f);
        }
        as[s] = fr;
    }
    z2p += __shfl_xor(z2p, 32);
    if (hi == 0) sTr[wv * 32 + lj] = -2.617e-3f * sqrtf(z2p);  // -2.32 sigma
    __syncthreads();

    int rloc[16];
    float TrW[16];
    #pragma unroll
    for (int q = 0; q < 16; ++q) {
        rloc[q] = wv * 32 + (q & 3) + 8 * (q >> 2) + 4 * hi;
        TrW[q] = sTr[rloc[q]];
    }

    const int jbase = jq * 256;
    float w2v[8];
    #pragma unroll
    for (int g = 0; g < 8; ++g) w2v[g] = w2[jbase + g * 32 + lj];

    uint safem = 0u;
    for (int g = 0; g < 8; ++g) {
        const ushort* bt = ebf_l + (size_t)(jq * 8 + g) * 8192;
        f32x16 acc = {};
        f32x16 acc2 = {};
        #pragma unroll
        for (int s = 0; s < 16; s += 2) {
            short8 bf  = *(const short8*)(bt + s * 512 + l * 8);
            short8 bf2 = *(const short8*)(bt + (s + 1) * 512 + l * 8);
            acc  = __builtin_amdgcn_mfma_f32_32x32x16_bf16(as[s],     bf,  acc,  0, 0, 0);
            acc2 = __builtin_amdgcn_mfma_f32_32x32x16_bf16(as[s + 1], bf2, acc2, 0, 0, 0);
        }
        const int j = jbase + g * 32 + lj;
        float sv[16];
        bool anyhit = false;
        #pragma unroll
        for (int q = 0; q < 16; ++q) {
            sv[q] = fmaf(-2.f, acc[q] + acc2[q], w2v[g]);
            anyhit = anyhit || (sv[q] <= TrW[q]);
        }
        if (__any(anyhit)) {
            #pragma unroll
            for (int q = 0; q < 16; ++q)
                if (sv[q] <= TrW[q]) {
                    uint pos = atomicAdd(&lcnt[rloc[q]], 1u);
                    if (pos < 16u) lcl[rloc[q]][pos] = (ushort)j;
                    if (sv[q] <= TrW[q] - 1.5e-3f) safem |= (1u << q);
                }
        }
    }

    #pragma unroll
    for (int off = 1; off < 32; off <<= 1) safem |= __shfl_xor(safem, off);
    if (lj == 0) {
        #pragma unroll
        for (int q = 0; q < 16; ++q)
            if (safem & (1u << q)) safeflag[rb * 128 + rloc[q]] = 1u;
    }
    __syncthreads();

    if (t < 128) {
        const uint lc = lcnt[t];
        const int n = rb * 128 + t;
        if (lc > 16u) atomicAdd(&candc[n], 100u);
        else if (lc) {
            uint base = atomicAdd(&candc[n], lc);
            for (uint i = 0; i < lc && base + i < 24u; ++i)
                lists[(size_t)n * 24 + base + i] = lcl[t][i];
        }
    }
}

// K2a: exact fp32 candidate argmin (bitwise chains). Safe rows resolved here;
// unsafe rows appended to fbq. Stage via global_load_lds (deep vmcnt queue).
__global__ __launch_bounds__(256) void vq_cand(const float* __restrict__ z,
                                               const float* __restrict__ w,
                                               const float* __restrict__ w2,
                                               const uint* __restrict__ candc,
                                               const uint* __restrict__ safeflag,
                                               const ushort* __restrict__ lists,
                                               uint* __restrict__ fbq,
                                               float* __restrict__ out,
                                               float* __restrict__ ws) {
    __shared__ float tile[256][64];
    __shared__ float sz2[64];
    __shared__ int scnt[64];
    __shared__ int soff[65];
    __shared__ uint swl[1536];
    __shared__ float sd[1536];

    const int t = threadIdx.x;
    const int n0 = blockIdx.x * 64;
    const int b = n0 >> 10, hw0 = n0 & 1023;

    {   // stage z tile transposed via global_load_lds: lane l dest = base + 16*l
        const int r4 = t & 15, cb = t >> 4;
        #pragma unroll
        for (int i = 0; i < 16; ++i) {
            const int c = i * 16 + cb;
            GLOAD_LDS16(z + ((size_t)(b * 256 + c) << 10) + hw0 + r4 * 4, &tile[c][r4 * 4]);
        }
    }
    __syncthreads();

    if (t < 64) {   // exact z2 (ascending k)
        float s = 0.f;
        for (int k = 0; k < 256; ++k) { float v = tile[k][t]; s = fmaf(v, v, s); }
        sz2[t] = s;
    }
    if (t < 64) {
        const int n = n0 + t;
        uint c = candc[n];
        bool fb = (safeflag[n] == 0u) || (c == 0u) || (c > 24u);
        scnt[t] = fb ? 0 : (int)c;
        if (fb) {
            uint slot = atomicAdd(fbq, 1u);
            fbq[1 + slot] = (uint)n;
        }
    }
    __syncthreads();
    if (t == 0) {
        int acc = 0;
        for (int r = 0; r < 64; ++r) { soff[r] = acc; acc += scnt[r]; }
        soff[64] = acc;
    }
    __syncthreads();
    if (t < 64) {
        const int o = soff[t], c = scnt[t], n = n0 + t;
        for (int i = 0; i < c; ++i) swl[o + i] = ((uint)t << 16) | (uint)lists[(size_t)n * 24 + i];
    }
    __syncthreads();

    const int total = soff[64];
    for (int e = t; e < total; e += 256) {
        const int r = (int)(swl[e] >> 16);
        const int j = (int)(swl[e] & 0xffffu);
        const float* wr = w + ((size_t)j << 8);
        float dot = 0.f;
        for (int k4 = 0; k4 < 64; ++k4) {
            float4 v = *(const float4*)(wr + k4 * 4);
            const int k0 = k4 * 4;
            dot = fmaf(v.x, tile[k0 + 0][r], dot);
            dot = fmaf(v.y, tile[k0 + 1][r], dot);
            dot = fmaf(v.z, tile[k0 + 2][r], dot);
            dot = fmaf(v.w, tile[k0 + 3][r], dot);
        }
        const float u = sz2[r] + w2[j];
        sd[e] = u - 2.0f * dot;
    }
    __syncthreads();

    if (t < 64 && scnt[t] > 0) {
        float db = 1e30f; int jb = 0;
        const int o = soff[t], c = scnt[t];
        for (int i = 0; i < c; ++i) {
            float d = sd[o + i];
            int j = (int)(swl[o + i] & 0xffffu);
            if (d < db || (d == db && j < jb)) { db = d; jb = j; }
        }
        const int n = n0 + t;
        out[IDX_OFF + n] = (float)jb;
        atomicAdd((uint*)ws + 64 + jb, 1u);
    }
}

// K2b: fallback rows via queue. Transposed codebook -> coalesced float4 j-lanes,
// ascending-k scalar fmaf chain (bitwise identical to validated path).
__global__ __launch_bounds__(256) void vq_fb(const float* __restrict__ z,
                                             const float* __restrict__ wt,
                                             const float* __restrict__ w2,
                                             const uint* __restrict__ fbq,
                                             float* __restrict__ out,
                                             float* __restrict__ ws) {
    __shared__ float zr[256];
    __shared__ float sz2s;
    __shared__ unsigned long long sred[4];

    const int t = threadIdx.x;
    const uint qn = fbq[0];
    for (uint qi = blockIdx.x; qi < qn; qi += 64) {
        const int n = (int)fbq[1 + qi];
        const int b = n >> 10, hw = n & 1023;
        __syncthreads();
        zr[t] = z[(size_t)b * 262144 + (size_t)t * 1024 + hw];
        __syncthreads();
        if (t == 0) {   // exact z2, ascending-k chain
            float s = 0.f;
            for (int k = 0; k < 256; ++k) { float v = zr[k]; s = fmaf(v, v, s); }
            sz2s = s;
        }
        __syncthreads();
        const float z2 = sz2s;

        float dt0 = 0.f, dt1 = 0.f, dt2 = 0.f, dt3 = 0.f;
        for (int k = 0; k < 256; ++k) {
            float4 wv = *(const float4*)(wt + ((size_t)k << 10) + t * 4);
            const float zk = zr[k];
            dt0 = fmaf(zk, wv.x, dt0);
            dt1 = fmaf(zk, wv.y, dt1);
            dt2 = fmaf(zk, wv.z, dt2);
            dt3 = fmaf(zk, wv.w, dt3);
        }
        const int j0 = t * 4;
        float dts[4] = {dt0, dt1, dt2, dt3};
        unsigned long long key = ~0ull;
        #pragma unroll
        for (int c = 0; c < 4; ++c) {
            const float u = z2 + w2[j0 + c];
            const float d = u - 2.0f * dts[c];
            unsigned long long kk = ((unsigned long long)__float_as_uint(d) << 32) | (uint)(j0 + c);
            if (kk < key) key = kk;
        }
        #pragma unroll
        for (int off = 32; off >= 1; off >>= 1) {
            unsigned long long ok = __shfl_xor(key, off);
            if (ok < key) key = ok;
        }
        if ((t & 63) == 0) sred[t >> 6] = key;
        __syncthreads();
        if (t == 0) {
            unsigned long long kk = sred[0];
            for (int i = 1; i < 4; ++i) if (sred[i] < kk) kk = sred[i];
            const int j = (int)(kk & 0xffffffffull);
            out[IDX_OFF + n] = (float)j;
            atomicAdd((uint*)ws + 64 + j, 1u);
        }
    }
}

// K2c: streaming epilogue, 32 rows/block, gl_lds stage, aligned dword z_q stores.
__global__ __launch_bounds__(256) void vq_emit(const float* __restrict__ z,
                                               const float* __restrict__ w,
                                               float* __restrict__ out,
                                               float* __restrict__ ws) {
    __shared__ float tile[256][32];
    __shared__ int sj[32];
    __shared__ float lred[4];

    const int t = threadIdx.x;
    const int n0 = blockIdx.x * 32;
    const int b = n0 >> 10, hw0 = n0 & 1023;

    if (t < 32) sj[t] = (int)out[IDX_OFF + n0 + t];
    {   // stage via global_load_lds: lane l dest = base + 16*l
        const int r4 = t & 7, cb = t >> 3;
        #pragma unroll
        for (int i = 0; i < 8; ++i) {
            const int c = i * 32 + cb;
            GLOAD_LDS16(z + ((size_t)(b * 256 + c) << 10) + hw0 + r4 * 4, &tile[c][r4 * 4]);
        }
    }
    __syncthreads();

    float lsum = 0.f;
    {
        const int r = t & 31, cq = t >> 5;
        const float* wrow = w + ((size_t)sj[r] << 8);
        for (int i = 0; i < 8; ++i) {
            const int c0 = (i * 8 + cq) * 4;
            float4 v = *(const float4*)(wrow + c0);
            float d0 = v.x - tile[c0 + 0][r];
            float d1 = v.y - tile[c0 + 1][r];
            float d2 = v.z - tile[c0 + 2][r];
            float d3 = v.w - tile[c0 + 3][r];
            lsum += d0 * d0 + d1 * d1 + d2 * d2 + d3 * d3;
            tile[c0 + 0][r] = v.x;
            tile[c0 + 1][r] = v.y;
            tile[c0 + 2][r] = v.z;
            tile[c0 + 3][r] = v.w;
        }
    }
    __syncthreads();

    {
        const int r = t & 31, ch = (t >> 5) & 1, wv = t >> 6;
        for (int i = 0; i < 32; ++i) {
            const int c = i * 8 + wv * 2 + ch;
            out[ZQ_OFF + ((size_t)(b * 256 + c) << 10) + hw0 + r] = tile[c][r];
        }
    }

    for (int off = 32; off >= 1; off >>= 1) lsum += __shfl_xor(lsum, off, 64);
    if ((t & 63) == 0) lred[t >> 6] = lsum;
    __syncthreads();
    if (t == 0) atomicAdd(ws, lred[0] + lred[1] + lred[2] + lred[3]);
}

__global__ __launch_bounds__(1024) void vq_fin(float* __restrict__ out,
                                               float* __restrict__ ws) {
    __shared__ float red[16];
    const int t = threadIdx.x;
    const uint cnt = ((const uint*)ws)[64 + t];
    const float e = (float)cnt * (1.0f / 32768.0f);
    float s = e * logf(e + 1e-10f);
    for (int off = 32; off >= 1; off >>= 1) s += __shfl_xor(s, off, 64);
    if ((t & 63) == 0) red[t >> 6] = s;
    __syncthreads();
    if (t == 0) {
        float H = 0.f;
        for (int i = 0; i < 16; ++i) H += red[i];
        out[PPLX_OFF] = expf(-H);
        const float l = ws[0] * (1.0f / 8388608.0f);
        out[0] = l + 0.25f * l;
    }
}

extern "C" void kernel_launch(void* const* d_in, const int* in_sizes, int n_in,
                              void* d_out, int out_size, void* d_ws, size_t ws_size,
                              hipStream_t stream) {
    const float* z = (const float*)d_in[0];   // (32,256,32,32) f32
    const float* w = (const float*)d_in[1];   // (1024,256) f32
    float* out = (float*)d_out;
    float* ws = (float*)d_ws;

    uint* candc = (uint*)((char*)d_ws + WS_CANDC);
    uint* safeflag = (uint*)((char*)d_ws + WS_FLAG);
    ushort* lists = (ushort*)((char*)d_ws + WS_LIST);
    float* w2 = (float*)((char*)d_ws + WS_W2);
    ushort* ebf_l = (ushort*)((char*)d_ws + WS_EBF);
    float* wt = (float*)((char*)d_ws + WS_WT);
    uint* fbq = (uint*)((char*)d_ws + WS_FBQ);

    vq_zero<<<64, 256, 0, stream>>>((uint*)d_ws);
    vq_prep_w2<<<16, 64, 0, stream>>>(w, w2);
    vq_prep_e<<<128, 256, 0, stream>>>(w, ebf_l);
    vq_prep_wt<<<1024, 256, 0, stream>>>(w, wt);
    vq_sweep<<<1024, 256, 0, stream>>>(z, ebf_l, w2, candc, safeflag, lists);
    vq_cand<<<512, 256, 0, stream>>>(z, w, w2, candc, safeflag, lists, fbq, out, ws);
    vq_fb<<<64, 256, 0, stream>>>(z, wt, w2, fbq, out, ws);
    vq_emit<<<1024, 256, 0, stream>>>(z, w, out, ws);
    vq_fin<<<1, 1024, 0, stream>>>(out, ws);
}